// Round 1
// baseline (287.691 us; speedup 1.0000x reference)
//
#include <hip/hip_runtime.h>
#include <hip/hip_bf16.h>
#include <stdint.h>

#define N_ROWS 8192
#define DIM 512
#define MARGIN_F 0.35f

typedef __attribute__((ext_vector_type(4))) float floatx4;
typedef __attribute__((ext_vector_type(8))) __bf16 bf16x8;

// order-preserving float->uint map (for atomicMin/Max on floats)
__device__ __forceinline__ unsigned enc_f(float f) {
    unsigned u = __float_as_uint(f);
    return (u & 0x80000000u) ? ~u : (u | 0x80000000u);
}
__device__ __forceinline__ float dec_f(unsigned e) {
    unsigned u = (e & 0x80000000u) ? (e ^ 0x80000000u) : ~e;
    return __uint_as_float(u);
}

__device__ __forceinline__ void load_lds16(const void* g, void* l) {
    __builtin_amdgcn_global_load_lds((__attribute__((address_space(1))) void*)(void*)g,
                                     (__attribute__((address_space(3))) void*)l, 16, 0, 0);
}

__global__ __launch_bounds__(256) void init_kernel(unsigned* minEnc, unsigned* maxEnc, float* ceSum) {
    int i = blockIdx.x * 256 + threadIdx.x;
    if (i < N_ROWS) { minEnc[i] = 0xFFFFFFFFu; maxEnc[i] = 0u; }
    if (i == 0) ceSum[0] = 0.f;
}

// One wave per row: CE (logsumexp - true logit) + bf16 conversion of the row.
__global__ __launch_bounds__(256) void rowstats_kernel(const float* __restrict__ x,
                                                       const int* __restrict__ label,
                                                       __bf16* __restrict__ abf,
                                                       float* __restrict__ ceSum) {
    int row = blockIdx.x * 4 + (threadIdx.x >> 6);
    int l = threadIdx.x & 63;
    const float* xr = x + (size_t)row * DIM;
    float4 v0 = ((const float4*)xr)[2 * l];
    float4 v1 = ((const float4*)xr)[2 * l + 1];
    float vals[8] = {v0.x, v0.y, v0.z, v0.w, v1.x, v1.y, v1.z, v1.w};

    float mx = vals[0];
#pragma unroll
    for (int i = 1; i < 8; i++) mx = fmaxf(mx, vals[i]);
#pragma unroll
    for (int s = 1; s < 64; s <<= 1) mx = fmaxf(mx, __shfl_xor(mx, s, 64));

    float se = 0.f;
#pragma unroll
    for (int i = 0; i < 8; i++) se += expf(vals[i] - mx);
#pragma unroll
    for (int s = 1; s < 64; s <<= 1) se += __shfl_xor(se, s, 64);

    // pack 8 bf16 (RNE) and store 16B
    unsigned hp[4];
#pragma unroll
    for (int i = 0; i < 4; i++) {
        unsigned u0 = __float_as_uint(vals[2 * i]);
        u0 += 0x7FFFu + ((u0 >> 16) & 1u);
        unsigned u1 = __float_as_uint(vals[2 * i + 1]);
        u1 += 0x7FFFu + ((u1 >> 16) & 1u);
        hp[i] = (u0 >> 16) | (u1 & 0xFFFF0000u);
    }
    ((uint4*)(abf + (size_t)row * DIM))[l] = make_uint4(hp[0], hp[1], hp[2], hp[3]);

    if (l == 0) {
        float tl = xr[label[row]];
        atomicAdd(ceSum, mx + logf(se) - tl);
    }
}

// 128x128 tile of G = A·A^T (bf16 MFMA), fused row-wise min-same / max-diff epilogue.
__global__ __launch_bounds__(256) void gemm_epi_kernel(const __bf16* __restrict__ A,
                                                       const int* __restrict__ label,
                                                       unsigned* __restrict__ minEnc,
                                                       unsigned* __restrict__ maxEnc) {
    __shared__ __bf16 As[128 * 32];
    __shared__ __bf16 Bs[128 * 32];
    __shared__ int labi[128], labj[128];
    __shared__ float redmn[256], redmx[256];

    int t = threadIdx.x;
    int ibase = blockIdx.y * 128, jbase = blockIdx.x * 128;
    if (t < 128) labi[t] = label[ibase + t];
    else labj[t - 128] = label[jbase + t - 128];

    int w = t >> 6, l = t & 63;
    int wm = w >> 1, wn = w & 1;
    int q = l >> 4, lm = l & 15;

    floatx4 acc[4][4];
#pragma unroll
    for (int a = 0; a < 4; a++)
#pragma unroll
        for (int b = 0; b < 4; b++) acc[a][b] = (floatx4)0.f;

    for (int kk = 0; kk < 16; kk++) {
        int k0 = kk * 32;
#pragma unroll
        for (int ro = 0; ro < 2; ro++) {
            int f = ro * 2048 + t * 8;       // element index into 128x32 tile
            int r = f >> 5, c = f & 31;
            load_lds16(A + (size_t)(ibase + r) * DIM + k0 + c, As + f);
            load_lds16(A + (size_t)(jbase + r) * DIM + k0 + c, Bs + f);
        }
        __syncthreads();

        bf16x8 af[4], bfv[4];
#pragma unroll
        for (int tm = 0; tm < 4; tm++)
            af[tm] = *(const bf16x8*)(As + (wm * 64 + tm * 16 + lm) * 32 + q * 8);
#pragma unroll
        for (int tn = 0; tn < 4; tn++)
            bfv[tn] = *(const bf16x8*)(Bs + (wn * 64 + tn * 16 + lm) * 32 + q * 8);
#pragma unroll
        for (int tm = 0; tm < 4; tm++)
#pragma unroll
            for (int tn = 0; tn < 4; tn++)
                acc[tm][tn] = __builtin_amdgcn_mfma_f32_16x16x32_bf16(af[tm], bfv[tn], acc[tm][tn], 0, 0, 0);
        __syncthreads();
    }

    // Epilogue: per output row, min over same-label G, max over diff-label G.
    // C/D layout: col = lane&15, row = (lane>>4)*4 + reg  [measured m89/m91]
#pragma unroll
    for (int tm = 0; tm < 4; tm++) {
#pragma unroll
        for (int r = 0; r < 4; r++) {
            int row_l = wm * 64 + tm * 16 + q * 4 + r;
            int li = labi[row_l];
            float mn = __builtin_inff(), mxv = -__builtin_inff();
#pragma unroll
            for (int tn = 0; tn < 4; tn++) {
                int cl = wn * 64 + tn * 16 + lm;
                float v = acc[tm][tn][r];
                bool same = (labj[cl] == li);
                mn = fminf(mn, same ? v : __builtin_inff());
                mxv = fmaxf(mxv, same ? -__builtin_inff() : v);
            }
#pragma unroll
            for (int s = 1; s < 16; s <<= 1) {
                mn = fminf(mn, __shfl_xor(mn, s, 64));
                mxv = fmaxf(mxv, __shfl_xor(mxv, s, 64));
            }
            if (lm == 0) { redmn[row_l * 2 + wn] = mn; redmx[row_l * 2 + wn] = mxv; }
        }
    }
    __syncthreads();
    if (t < 128) {
        float mn = fminf(redmn[2 * t], redmn[2 * t + 1]);
        float mxv = fmaxf(redmx[2 * t], redmx[2 * t + 1]);
        atomicMin(&minEnc[ibase + t], enc_f(mn));
        atomicMax(&maxEnc[ibase + t], enc_f(mxv));
    }
}

__global__ __launch_bounds__(256) void finalize_kernel(const unsigned* __restrict__ minEnc,
                                                       const unsigned* __restrict__ maxEnc,
                                                       const float* __restrict__ ceSum,
                                                       float* __restrict__ out) {
    float s = 0.f;
    for (int i = threadIdx.x; i < N_ROWS; i += 256) {
        float mn = dec_f(minEnc[i]);
        float mxv = dec_f(maxEnc[i]);
        // pos - neg = 2*(max_diff G - min_same G)  (sq_i cancels; sq_j ≈ 1, dev ~1e-7)
        float h = 2.0f * (mxv - mn) + MARGIN_F;
        s += fmaxf(h, 0.f);
    }
#pragma unroll
    for (int sh = 1; sh < 64; sh <<= 1) s += __shfl_xor(s, sh, 64);
    __shared__ float red[4];
    int w = threadIdx.x >> 6, l = threadIdx.x & 63;
    if (l == 0) red[w] = s;
    __syncthreads();
    if (threadIdx.x == 0) {
        float tot = red[0] + red[1] + red[2] + red[3];
        out[0] = (tot + ceSum[0]) / (float)N_ROWS;
    }
}

extern "C" void kernel_launch(void* const* d_in, const int* in_sizes, int n_in,
                              void* d_out, int out_size, void* d_ws, size_t ws_size,
                              hipStream_t stream) {
    const float* x = (const float*)d_in[0];
    const int* label = (const int*)d_in[1];
    float* out = (float*)d_out;

    char* ws = (char*)d_ws;
    __bf16* abf = (__bf16*)ws;                                   // 8 MB bf16 copy of input
    unsigned* minEnc = (unsigned*)(ws + (size_t)N_ROWS * DIM * 2);
    unsigned* maxEnc = minEnc + N_ROWS;
    float* ceSum = (float*)(maxEnc + N_ROWS);

    init_kernel<<<N_ROWS / 256, 256, 0, stream>>>(minEnc, maxEnc, ceSum);
    rowstats_kernel<<<N_ROWS / 4, 256, 0, stream>>>(x, label, abf, ceSum);
    gemm_epi_kernel<<<dim3(64, 64), 256, 0, stream>>>(abf, label, minEnc, maxEnc);
    finalize_kernel<<<1, 256, 0, stream>>>(minEnc, maxEnc, ceSum, out);
}

// Round 2
// 154.043 us; speedup vs baseline: 1.8676x; 1.8676x over previous
//
#include <hip/hip_runtime.h>
#include <hip/hip_bf16.h>
#include <stdint.h>

#define N_ROWS 8192
#define DIM 512
#define MARGIN_F 0.35f
#define NBLK 64                 // 8192/128 row-blocks
#define NTRI (NBLK * (NBLK + 1) / 2)   // 2080 triangle blocks
#define ROWSTAT_BLOCKS (N_ROWS / 4)    // 2048

typedef __attribute__((ext_vector_type(4))) float floatx4;
typedef __attribute__((ext_vector_type(8))) __bf16 bf16x8;

// order-preserving float->uint map (for atomicMin/Max on floats)
__device__ __forceinline__ unsigned enc_f(float f) {
    unsigned u = __float_as_uint(f);
    return (u & 0x80000000u) ? ~u : (u | 0x80000000u);
}
__device__ __forceinline__ float dec_f(unsigned e) {
    unsigned u = (e & 0x80000000u) ? (e ^ 0x80000000u) : ~e;
    return __uint_as_float(u);
}

__device__ __forceinline__ void load_lds16(const void* g, void* l) {
    __builtin_amdgcn_global_load_lds((__attribute__((address_space(1))) void*)(void*)g,
                                     (__attribute__((address_space(3))) void*)l, 16, 0, 0);
}

// One wave per row: CE (logsumexp - true logit) + bf16 conversion of the row.
// Per-BLOCK CE partial (no contended atomics). Also folds in min/max init.
__global__ __launch_bounds__(256) void rowstats_kernel(const float* __restrict__ x,
                                                       const int* __restrict__ label,
                                                       __bf16* __restrict__ abf,
                                                       unsigned* __restrict__ minEnc,
                                                       unsigned* __restrict__ maxEnc,
                                                       float* __restrict__ cePartial) {
    int gid = blockIdx.x * 256 + threadIdx.x;
    if (gid < N_ROWS) { minEnc[gid] = 0xFFFFFFFFu; maxEnc[gid] = 0u; }

    int w = threadIdx.x >> 6;
    int row = blockIdx.x * 4 + w;
    int l = threadIdx.x & 63;
    const float* xr = x + (size_t)row * DIM;
    float4 v0 = ((const float4*)xr)[2 * l];
    float4 v1 = ((const float4*)xr)[2 * l + 1];
    float vals[8] = {v0.x, v0.y, v0.z, v0.w, v1.x, v1.y, v1.z, v1.w};

    float mx = vals[0];
#pragma unroll
    for (int i = 1; i < 8; i++) mx = fmaxf(mx, vals[i]);
#pragma unroll
    for (int s = 1; s < 64; s <<= 1) mx = fmaxf(mx, __shfl_xor(mx, s, 64));

    float se = 0.f;
#pragma unroll
    for (int i = 0; i < 8; i++) se += expf(vals[i] - mx);
#pragma unroll
    for (int s = 1; s < 64; s <<= 1) se += __shfl_xor(se, s, 64);

    // pack 8 bf16 (RNE) and store 16B
    unsigned hp[4];
#pragma unroll
    for (int i = 0; i < 4; i++) {
        unsigned u0 = __float_as_uint(vals[2 * i]);
        u0 += 0x7FFFu + ((u0 >> 16) & 1u);
        unsigned u1 = __float_as_uint(vals[2 * i + 1]);
        u1 += 0x7FFFu + ((u1 >> 16) & 1u);
        hp[i] = (u0 >> 16) | (u1 & 0xFFFF0000u);
    }
    ((uint4*)(abf + (size_t)row * DIM))[l] = make_uint4(hp[0], hp[1], hp[2], hp[3]);

    __shared__ float wsum[4];
    if (l == 0) {
        float tl = xr[label[row]];
        wsum[w] = mx + logf(se) - tl;
    }
    __syncthreads();
    if (threadIdx.x == 0)
        cePartial[blockIdx.x] = wsum[0] + wsum[1] + wsum[2] + wsum[3];
}

// Lower-triangle 128x128 tile of G = A·A^T (bf16 MFMA, BK=64, XOR-swizzled LDS),
// dual fused epilogue: updates min-same/max-diff for both I-rows and J-rows.
__global__ __launch_bounds__(256) void gemm_epi_kernel(const __bf16* __restrict__ A,
                                                       const int* __restrict__ label,
                                                       unsigned* __restrict__ minEnc,
                                                       unsigned* __restrict__ maxEnc) {
    __shared__ __bf16 As[128 * 64];
    __shared__ __bf16 Bs[128 * 64];
    __shared__ int labi[128], labj[128];
    __shared__ float redImn[128][2], redImx[128][2];
    __shared__ float redJmn[128][2], redJmx[128][2];

    // triangle decode: bi >= bj
    int b = blockIdx.x;
    int bi = (int)((sqrtf(8.0f * (float)b + 1.0f) - 1.0f) * 0.5f);
    while ((bi + 1) * (bi + 2) / 2 <= b) bi++;
    while (bi * (bi + 1) / 2 > b) bi--;
    int bj = b - bi * (bi + 1) / 2;
    int ibase = bi * 128, jbase = bj * 128;

    int t = threadIdx.x;
    if (t < 128) labi[t] = label[ibase + t];
    else labj[t - 128] = label[jbase + t - 128];

    int w = t >> 6, l = t & 63;
    int wm = w >> 1, wn = w & 1;
    int q = l >> 4, lm = l & 15;

    floatx4 acc[4][4];
#pragma unroll
    for (int a = 0; a < 4; a++)
#pragma unroll
        for (int c = 0; c < 4; c++) acc[a][c] = (floatx4)0.f;

    for (int kk = 0; kk < 8; kk++) {
        int k0 = kk * 64;
#pragma unroll
        for (int i2 = 0; i2 < 4; i2++) {
            int s = i2 * 256 + t;       // 16B-chunk slot in 128x64 tile
            int r = s >> 3;
            int cg = (s & 7) ^ (r & 7); // global chunk for this slot (XOR swizzle)
            load_lds16(A + (size_t)(ibase + r) * DIM + k0 + cg * 8, As + s * 8);
            load_lds16(A + (size_t)(jbase + r) * DIM + k0 + cg * 8, Bs + s * 8);
        }
        __syncthreads();

#pragma unroll
        for (int ks = 0; ks < 2; ks++) {
            bf16x8 af[4], bfv[4];
#pragma unroll
            for (int tm = 0; tm < 4; tm++) {
                int R = wm * 64 + tm * 16 + lm;
                af[tm] = *(const bf16x8*)(As + R * 64 + (((ks * 4 + q) ^ (R & 7)) * 8));
            }
#pragma unroll
            for (int tn = 0; tn < 4; tn++) {
                int R = wn * 64 + tn * 16 + lm;
                bfv[tn] = *(const bf16x8*)(Bs + R * 64 + (((ks * 4 + q) ^ (R & 7)) * 8));
            }
#pragma unroll
            for (int tm = 0; tm < 4; tm++)
#pragma unroll
                for (int tn = 0; tn < 4; tn++)
                    acc[tm][tn] = __builtin_amdgcn_mfma_f32_16x16x32_bf16(af[tm], bfv[tn], acc[tm][tn], 0, 0, 0);
        }
        __syncthreads();
    }

    // Dual epilogue. C/D layout: col = lane&15, row = (lane>>4)*4 + reg [m89/m91]
    const float INF = __builtin_inff();
    int jlab[4];
#pragma unroll
    for (int tn = 0; tn < 4; tn++) jlab[tn] = labj[wn * 64 + tn * 16 + lm];

    float mnJ[4], mxJ[4];
#pragma unroll
    for (int tn = 0; tn < 4; tn++) { mnJ[tn] = INF; mxJ[tn] = -INF; }

#pragma unroll
    for (int tm = 0; tm < 4; tm++) {
#pragma unroll
        for (int r = 0; r < 4; r++) {
            int row_l = wm * 64 + tm * 16 + q * 4 + r;
            int il = labi[row_l];
            float mnI = INF, mxI = -INF;
#pragma unroll
            for (int tn = 0; tn < 4; tn++) {
                float v = acc[tm][tn][r];
                bool same = (jlab[tn] == il);
                mnI = fminf(mnI, same ? v : INF);
                mxI = fmaxf(mxI, same ? -INF : v);
                mnJ[tn] = fminf(mnJ[tn], same ? v : INF);
                mxJ[tn] = fmaxf(mxJ[tn], same ? -INF : v);
            }
#pragma unroll
            for (int s = 1; s < 16; s <<= 1) {
                mnI = fminf(mnI, __shfl_xor(mnI, s, 64));
                mxI = fmaxf(mxI, __shfl_xor(mxI, s, 64));
            }
            if (lm == 0) { redImn[row_l][wn] = mnI; redImx[row_l][wn] = mxI; }
        }
    }
#pragma unroll
    for (int tn = 0; tn < 4; tn++) {
#pragma unroll
        for (int s = 16; s < 64; s <<= 1) {
            mnJ[tn] = fminf(mnJ[tn], __shfl_xor(mnJ[tn], s, 64));
            mxJ[tn] = fmaxf(mxJ[tn], __shfl_xor(mxJ[tn], s, 64));
        }
        if (q == 0) {
            int col_l = wn * 64 + tn * 16 + lm;
            redJmn[col_l][wm] = mnJ[tn];
            redJmx[col_l][wm] = mxJ[tn];
        }
    }
    __syncthreads();
    if (t < 128) {
        float mnI = fminf(redImn[t][0], redImn[t][1]);
        float mxI = fmaxf(redImx[t][0], redImx[t][1]);
        atomicMin(&minEnc[ibase + t], enc_f(mnI));
        atomicMax(&maxEnc[ibase + t], enc_f(mxI));
        float mnJ2 = fminf(redJmn[t][0], redJmn[t][1]);
        float mxJ2 = fmaxf(redJmx[t][0], redJmx[t][1]);
        atomicMin(&minEnc[jbase + t], enc_f(mnJ2));
        atomicMax(&maxEnc[jbase + t], enc_f(mxJ2));
    }
}

__global__ __launch_bounds__(256) void finalize_kernel(const unsigned* __restrict__ minEnc,
                                                       const unsigned* __restrict__ maxEnc,
                                                       const float* __restrict__ cePartial,
                                                       float* __restrict__ out) {
    float s = 0.f;
    for (int i = threadIdx.x; i < N_ROWS; i += 256) {
        float mn = dec_f(minEnc[i]);
        float mxv = dec_f(maxEnc[i]);
        // pos - neg = 2*(max_diff G - min_same G); sq_i cancels, sq_j ≈ 1 (dev ~1e-7)
        float h = 2.0f * (mxv - mn) + MARGIN_F;
        s += fmaxf(h, 0.f);
    }
    float ce = 0.f;
    for (int i = threadIdx.x; i < ROWSTAT_BLOCKS; i += 256) ce += cePartial[i];
    s += ce;
#pragma unroll
    for (int sh = 1; sh < 64; sh <<= 1) s += __shfl_xor(s, sh, 64);
    __shared__ float red[4];
    int w = threadIdx.x >> 6, l = threadIdx.x & 63;
    if (l == 0) red[w] = s;
    __syncthreads();
    if (threadIdx.x == 0)
        out[0] = (red[0] + red[1] + red[2] + red[3]) / (float)N_ROWS;
}

extern "C" void kernel_launch(void* const* d_in, const int* in_sizes, int n_in,
                              void* d_out, int out_size, void* d_ws, size_t ws_size,
                              hipStream_t stream) {
    const float* x = (const float*)d_in[0];
    const int* label = (const int*)d_in[1];
    float* out = (float*)d_out;

    char* ws = (char*)d_ws;
    __bf16* abf = (__bf16*)ws;                                   // 8 MB bf16 copy of input
    unsigned* minEnc = (unsigned*)(ws + (size_t)N_ROWS * DIM * 2);
    unsigned* maxEnc = minEnc + N_ROWS;
    float* cePartial = (float*)(maxEnc + N_ROWS);                // 2048 floats

    rowstats_kernel<<<ROWSTAT_BLOCKS, 256, 0, stream>>>(x, label, abf, minEnc, maxEnc, cePartial);
    gemm_epi_kernel<<<NTRI, 256, 0, stream>>>(abf, label, minEnc, maxEnc);
    finalize_kernel<<<1, 256, 0, stream>>>(minEnc, maxEnc, cePartial, out);
}